// Round 1
// baseline (65.780 us; speedup 1.0000x reference)
//
#include <hip/hip_runtime.h>

// Problem constants (from reference): B=8, S=4096, D=1024, A=3, C=2, K=64, MARGIN=5
#define DIM      1024
#define NROWS    32768      // B*S
#define SA       12288      // S*A per batch
#define KSAMP    64
#define PRED_OFF 1          // d_out layout: [loss(1) | predict(98304) | total_idx(1536) | cand(512)]
#define TI_OFF   (1 + 98304)
#define CAND_OFF (1 + 98304 + 1536)

// ---------------- K1: fused linear projection + argmax(predict_label) ----------------
// grid 1024 x 256. Each block: 32 rows. wave(4)/block, each wave: 8 rows (4 pairs x 2).
// lane: q = lane&15 slices D into 16 chunks of 64; p = lane>>4 picks the row pair.
// W (1024x6) staged transposed in LDS: lds_w[c*1024 + d]. b128 reads at banks 4q mod 32
// -> 2-way conflict (free per m136), p-lanes broadcast.
__global__ __launch_bounds__(256, 4)
void k_gemm_pred(const float* __restrict__ X, const float* __restrict__ W,
                 const float* __restrict__ bias, float* __restrict__ outPred) {
  __shared__ float lds_w[6 * 1024];
  for (int i = threadIdx.x; i < 1536; i += 256) {
    float4 v = reinterpret_cast<const float4*>(W)[i];
    float vv[4] = {v.x, v.y, v.z, v.w};
    int e0 = i * 4;
#pragma unroll
    for (int k = 0; k < 4; ++k) {
      int e = e0 + k;
      int d = e / 6;
      int c = e - 6 * d;
      lds_w[c * 1024 + d] = vv[k];
    }
  }
  __syncthreads();

  const int tid  = threadIdx.x;
  const int wave = tid >> 6;
  const int lane = tid & 63;
  const int q    = lane & 15;
  const int p    = lane >> 4;
  const int row0 = blockIdx.x * 32 + wave * 8 + p * 2;
  const float* x0 = X + (size_t)row0 * DIM;
  const float* x1 = x0 + DIM;
  const int qb = q * 4;

  double acc[12];
#pragma unroll
  for (int i = 0; i < 12; ++i) acc[i] = 0.0;

#pragma unroll 2
  for (int j = 0; j < 16; ++j) {
    const int d = j * 64 + qb;
    const float4 a4 = *reinterpret_cast<const float4*>(x0 + d);
    const float4 b4 = *reinterpret_cast<const float4*>(x1 + d);
    const double ax0 = a4.x, ax1 = a4.y, ax2 = a4.z, ax3 = a4.w;
    const double bx0 = b4.x, bx1 = b4.y, bx2 = b4.z, bx3 = b4.w;
#pragma unroll
    for (int c = 0; c < 6; ++c) {
      const float4 wv = *reinterpret_cast<const float4*>(&lds_w[c * 1024 + d]);
      const double w0 = wv.x, w1 = wv.y, w2 = wv.z, w3 = wv.w;
      acc[c]     += ax0 * w0 + ax1 * w1 + ax2 * w2 + ax3 * w3;
      acc[6 + c] += bx0 * w0 + bx1 * w1 + bx2 * w2 + bx3 * w3;
    }
  }

  // reduce across the 16 q-lanes (lane bits 0..3); p bits preserved
#pragma unroll
  for (int s = 1; s < 16; s <<= 1) {
#pragma unroll
    for (int i = 0; i < 12; ++i) acc[i] += __shfl_xor(acc[i], s, 64);
  }

  if (q == 0) {
#pragma unroll
    for (int r = 0; r < 2; ++r) {
      const int row = row0 + r;
      float l[6];
#pragma unroll
      for (int c = 0; c < 6; ++c) l[c] = (float)(acc[r * 6 + c] + (double)bias[c]);
#pragma unroll
      for (int a = 0; a < 3; ++a)
        outPred[(size_t)row * 3 + a] = (l[2 * a + 1] > l[2 * a]) ? 1.0f : 0.0f;
    }
  }
}

// ---------------- K2: per-batch first-64-positives + sampled outputs + loss partials --
// All positive anchors have forced class-1 score 2.0 (> sigmoid) and there are ~6144
// per batch >> 64, so top_k (lowest-index tie-break) == first 64 positives in flat order.
// grid 8 x 512 (8 waves). Wave 0 ballot-scans labels into LDS; then each wave computes
// 8 samples: recompute the 2 sampled logits (wave-parallel dot), margin term,
// total_idx, candidate_label (read back from predict region for exact consistency).
__global__ __launch_bounds__(512)
void k_sample(const float* __restrict__ X, const float* __restrict__ W,
              const float* __restrict__ bias, const int* __restrict__ labels,
              const float* __restrict__ pred, float* __restrict__ outTI,
              float* __restrict__ outCand, float* __restrict__ partial) {
  __shared__ int   s_pos[KSAMP];
  __shared__ float s_wsum[8];
  const int b    = blockIdx.x;
  const int tid  = threadIdx.x;
  const int wave = tid >> 6;
  const int lane = tid & 63;

  if (wave == 0) {
    int found = 0;
    for (int base = 0; base < SA && found < KSAMP; base += 64) {
      const int lab = labels[b * SA + base + lane];
      const unsigned long long m = __ballot(lab == 1);
      if (lab == 1) {
        const int rank = __popcll(m & ((1ull << lane) - 1ull));
        const int pos = found + rank;
        if (pos < KSAMP) s_pos[pos] = base + lane;
      }
      found += __popcll(m);
    }
  }
  __syncthreads();

  float acc = 0.0f;
  for (int k = wave; k < KSAMP; k += 8) {
    const int pos = s_pos[k];
    const int seq = pos / 3;
    const int anc = pos - seq * 3;
    const int c0  = anc * 2;
    const float* xr = X + ((size_t)b * 4096 + seq) * DIM;
    float s0 = 0.0f, s1 = 0.0f;
#pragma unroll
    for (int dd = 0; dd < 4; ++dd) {
      const int d = (dd * 64 + lane) * 4;
      const float4 xv = *reinterpret_cast<const float4*>(xr + d);
      const float xe[4] = {xv.x, xv.y, xv.z, xv.w};
#pragma unroll
      for (int e = 0; e < 4; ++e) {
        s0 += xe[e] * W[(d + e) * 6 + c0];
        s1 += xe[e] * W[(d + e) * 6 + c0 + 1];
      }
    }
#pragma unroll
    for (int sft = 1; sft < 64; sft <<= 1) {
      s0 += __shfl_xor(s0, sft, 64);
      s1 += __shfl_xor(s1, sft, 64);
    }
    const float l0 = s0 + bias[c0];
    const float l1 = s1 + bias[c0 + 1];
    const int y = labels[b * SA + pos];           // 1 by construction
    const float xy = y ? l1 : l0;
    const float xo = y ? l0 : l1;
    acc += fmaxf(0.0f, 5.0f - xy + xo);
    if (lane == 0) {
      const int gk = b * KSAMP + k;
      outTI[gk * 3 + 0] = (float)b;
      outTI[gk * 3 + 1] = (float)seq;
      outTI[gk * 3 + 2] = (float)anc;
      outCand[gk] = pred[((size_t)b * 4096 + seq) * 3 + anc];
    }
  }
  if (lane == 0) s_wsum[wave] = acc;
  __syncthreads();
  if (tid == 0) {
    float t = 0.0f;
#pragma unroll
    for (int w = 0; w < 8; ++w) t += s_wsum[w];
    partial[b] = t;
  }
}

// ---------------- K3: deterministic loss finalize ----------------
// loss = mean over 512 samples of (term / C=2)  ->  sum(term) / 1024
__global__ void k_final(const float* __restrict__ partial, float* __restrict__ out0) {
  if (threadIdx.x == 0) {
    float t = 0.0f;
#pragma unroll
    for (int b = 0; b < 8; ++b) t += partial[b];
    out0[0] = t * (1.0f / 1024.0f);
  }
}

extern "C" void kernel_launch(void* const* d_in, const int* in_sizes, int n_in,
                              void* d_out, int out_size, void* d_ws, size_t ws_size,
                              hipStream_t stream) {
  const float* X     = (const float*)d_in[0];
  const float* W     = (const float*)d_in[1];
  const float* bias  = (const float*)d_in[2];
  const int*   lab   = (const int*)d_in[3];
  float* out = (float*)d_out;
  float* partial = (float*)d_ws;   // 8 floats

  k_gemm_pred<<<1024, 256, 0, stream>>>(X, W, bias, out + PRED_OFF);
  k_sample<<<8, 512, 0, stream>>>(X, W, bias, lab, out + PRED_OFF,
                                  out + TI_OFF, out + CAND_OFF, partial);
  k_final<<<1, 64, 0, stream>>>(partial, out);
}

// Round 2
// 33.126 us; speedup vs baseline: 1.9858x; 1.9858x over previous
//
#include <hip/hip_runtime.h>

// Problem constants: B=8, S=4096, D=1024, A=3, C=2, K=64, MARGIN=5
#define DIM      1024
#define NROWS    32768      // B*S
#define SA       12288      // S*A per batch
#define KSAMP    64
#define PRED_OFF 1          // d_out layout: [loss(1) | predict(98304) | total_idx(1536) | cand(512)]
#define TI_OFF   (1 + 98304)
#define CAND_OFF (1 + 98304 + 1536)

// ---------------- K1: fused linear projection + argmax + logits dump ----------------
// grid 1024 x 256. Block: 32 rows; wave: 8 rows (4 p-pairs x 2). q = lane&15 slices D
// into 16 chunks of 64. W staged transposed in LDS ([c][d], f32). f64 accumulation
// (matched reference argmax exactly at round 1 — keep FMA order identical).
// NEW: full per-row logits (f32) written to ws so the sampling kernel never touches X/W.
__global__ __launch_bounds__(256, 4)
void k_gemm_pred(const float* __restrict__ X, const float* __restrict__ W,
                 const float* __restrict__ bias, float* __restrict__ outPred,
                 float* __restrict__ logits) {
  __shared__ float lds_w[6 * 1024];
  for (int i = threadIdx.x; i < 1536; i += 256) {
    float4 v = reinterpret_cast<const float4*>(W)[i];
    float vv[4] = {v.x, v.y, v.z, v.w};
    int e0 = i * 4;
#pragma unroll
    for (int k = 0; k < 4; ++k) {
      int e = e0 + k;
      int d = e / 6;
      int c = e - 6 * d;
      lds_w[c * 1024 + d] = vv[k];
    }
  }
  __syncthreads();

  const int tid  = threadIdx.x;
  const int wave = tid >> 6;
  const int lane = tid & 63;
  const int q    = lane & 15;
  const int p    = lane >> 4;
  const int row0 = blockIdx.x * 32 + wave * 8 + p * 2;
  const float* x0 = X + (size_t)row0 * DIM;
  const float* x1 = x0 + DIM;
  const int qb = q * 4;

  double acc[12];
#pragma unroll
  for (int i = 0; i < 12; ++i) acc[i] = 0.0;

#pragma unroll 4
  for (int j = 0; j < 16; ++j) {
    const int d = j * 64 + qb;
    const float4 a4 = *reinterpret_cast<const float4*>(x0 + d);
    const float4 b4 = *reinterpret_cast<const float4*>(x1 + d);
    const double ax0 = a4.x, ax1 = a4.y, ax2 = a4.z, ax3 = a4.w;
    const double bx0 = b4.x, bx1 = b4.y, bx2 = b4.z, bx3 = b4.w;
#pragma unroll
    for (int c = 0; c < 6; ++c) {
      const float4 wv = *reinterpret_cast<const float4*>(&lds_w[c * 1024 + d]);
      const double w0 = wv.x, w1 = wv.y, w2 = wv.z, w3 = wv.w;
      acc[c]     += ax0 * w0 + ax1 * w1 + ax2 * w2 + ax3 * w3;
      acc[6 + c] += bx0 * w0 + bx1 * w1 + bx2 * w2 + bx3 * w3;
    }
  }

  // butterfly across the 16 q-lanes (lane bits 0..3); all lanes end with totals
#pragma unroll
  for (int s = 1; s < 16; s <<= 1) {
#pragma unroll
    for (int i = 0; i < 12; ++i) acc[i] += __shfl_xor(acc[i], s, 64);
  }

  // logits dump: lanes q<6 write row0's class q; lanes 8..13 write row1's class q-8
  if (q < 6) {
    logits[(size_t)row0 * 6 + q] = (float)(acc[q] + (double)bias[q]);
  } else if (q >= 8 && q < 14) {
    const int c = q - 8;
    logits[(size_t)(row0 + 1) * 6 + c] = (float)(acc[6 + c] + (double)bias[c]);
  }

  if (q == 0) {
#pragma unroll
    for (int r = 0; r < 2; ++r) {
      const int row = row0 + r;
      float l[6];
#pragma unroll
      for (int c = 0; c < 6; ++c) l[c] = (float)(acc[r * 6 + c] + (double)bias[c]);
#pragma unroll
      for (int a = 0; a < 3; ++a)
        outPred[(size_t)row * 3 + a] = (l[2 * a + 1] > l[2 * a]) ? 1.0f : 0.0f;
    }
  }
}

// ---------------- K2: scan + gather + loss, single block ----------------
// Every positive anchor's class-1 score is forced to 2.0 (> any sigmoid), and there are
// ~6144 positives per batch >> 64, so top_k (lowest-index tie-break) == first 64
// positives in flat order. Wave w owns batch w: ballot-scan labels (~2-3 chunks),
// then lane k handles sample k entirely from precomputed logits. Butterfly-reduce the
// margin terms, then thread 0 finalizes the loss: mean(term/C) = sum/(512*2).
__global__ __launch_bounds__(512)
void k_sample_final(const int* __restrict__ labels, const float* __restrict__ logits,
                    const float* __restrict__ pred, float* __restrict__ outTI,
                    float* __restrict__ outCand, float* __restrict__ out0) {
  __shared__ int   s_pos[8][KSAMP];
  __shared__ float s_part[8];
  const int tid  = threadIdx.x;
  const int w    = tid >> 6;       // batch
  const int lane = tid & 63;

  int found = 0;
  for (int base = 0; base < SA && found < KSAMP; base += 64) {
    const int lab = labels[w * SA + base + lane];
    const unsigned long long m = __ballot(lab == 1);
    if (lab == 1) {
      const int rank = __popcll(m & ((1ull << lane) - 1ull));
      const int pos = found + rank;
      if (pos < KSAMP) s_pos[w][pos] = base + lane;
    }
    found += __popcll(m);
  }
  __syncthreads();

  const int pos = s_pos[w][lane];
  const int seq = pos / 3;
  const int anc = pos - seq * 3;
  const int c0  = anc * 2;
  const size_t rbase = ((size_t)w * 4096 + seq);
  const float l0 = logits[rbase * 6 + c0];
  const float l1 = logits[rbase * 6 + c0 + 1];
  // sampled label is 1 by construction (we selected label==1 positions)
  const float term = fmaxf(0.0f, 5.0f - l1 + l0);

  const int gk = w * KSAMP + lane;
  outTI[gk * 3 + 0] = (float)w;
  outTI[gk * 3 + 1] = (float)seq;
  outTI[gk * 3 + 2] = (float)anc;
  outCand[gk] = pred[rbase * 3 + anc];

  float t = term;
#pragma unroll
  for (int s = 1; s < 64; s <<= 1) t += __shfl_xor(t, s, 64);
  if (lane == 0) s_part[w] = t;
  __syncthreads();
  if (tid == 0) {
    float tot = 0.0f;
#pragma unroll
    for (int i = 0; i < 8; ++i) tot += s_part[i];
    out0[0] = tot * (1.0f / 1024.0f);   // /512 samples /C=2
  }
}

extern "C" void kernel_launch(void* const* d_in, const int* in_sizes, int n_in,
                              void* d_out, int out_size, void* d_ws, size_t ws_size,
                              hipStream_t stream) {
  const float* X     = (const float*)d_in[0];
  const float* W     = (const float*)d_in[1];
  const float* bias  = (const float*)d_in[2];
  const int*   lab   = (const int*)d_in[3];
  float* out    = (float*)d_out;
  float* logits = (float*)d_ws;    // 32768*6 floats = 768 KB

  k_gemm_pred<<<1024, 256, 0, stream>>>(X, W, bias, out + PRED_OFF, logits);
  k_sample_final<<<1, 512, 0, stream>>>(lab, logits, out + PRED_OFF,
                                        out + TI_OFF, out + CAND_OFF, out);
}

// Round 3
// 30.701 us; speedup vs baseline: 2.1426x; 1.0790x over previous
//
#include <hip/hip_runtime.h>

// Problem constants: B=8, S=4096, D=1024, A=3, C=2, K=64, MARGIN=5
#define DIM      1024
#define NROWS    32768      // B*S
#define SA       12288      // S*A per batch
#define KSAMP    64
#define PRED_OFF 1          // d_out layout: [loss(1) | predict(98304) | total_idx(1536) | cand(512)]
#define TI_OFF   (1 + 98304)
#define CAND_OFF (1 + 98304 + 1536)

// ---------------- K1: fused linear projection, DIFF form ----------------
// Everything downstream needs only ldiff[a] = l[2a+1] - l[2a]:
//   predict = (ldiff>0), candidate = same, margin(y=1) = max(0, 5 - ldiff).
// So compute 3 dots per row against wd_a = W[:,2a+1]-W[:,2a] (staged in LDS, f32;
// per-element diff rounding adds ~4e-8 RMS to the dot — same order as the passing
// f64 path, argmax consistency vs np unchanged). f64 accumulation, identical
// reduction tree to the passing round-2 kernel.
// grid 1024 x 256. Block: 32 rows; wave: 8 rows (4 p-pairs x 2). q=lane&15 slices
// D into 16 chunks of 64. LDS float4 reads: banks 4q..4q+3 -> 2-way (free).
__global__ __launch_bounds__(256, 4)
void k_gemm_pred(const float* __restrict__ X, const float* __restrict__ W,
                 const float* __restrict__ bias, float* __restrict__ outPred,
                 float* __restrict__ ldiff) {
  __shared__ float lds_wd[3 * 1024];
  for (int d = threadIdx.x; d < 1024; d += 256) {
    const float2 w01 = *reinterpret_cast<const float2*>(W + d * 6);     // 8B aligned
    const float2 w23 = *reinterpret_cast<const float2*>(W + d * 6 + 2);
    const float2 w45 = *reinterpret_cast<const float2*>(W + d * 6 + 4);
    lds_wd[0 * 1024 + d] = w01.y - w01.x;
    lds_wd[1 * 1024 + d] = w23.y - w23.x;
    lds_wd[2 * 1024 + d] = w45.y - w45.x;
  }
  __syncthreads();

  const int tid  = threadIdx.x;
  const int wave = tid >> 6;
  const int lane = tid & 63;
  const int q    = lane & 15;
  const int p    = lane >> 4;
  const int row0 = blockIdx.x * 32 + wave * 8 + p * 2;
  const float* x0 = X + (size_t)row0 * DIM;
  const float* x1 = x0 + DIM;
  const int qb = q * 4;

  double acc[6];
#pragma unroll
  for (int i = 0; i < 6; ++i) acc[i] = 0.0;

#pragma unroll 4
  for (int j = 0; j < 16; ++j) {
    const int d = j * 64 + qb;
    const float4 a4 = *reinterpret_cast<const float4*>(x0 + d);
    const float4 b4 = *reinterpret_cast<const float4*>(x1 + d);
    const double ax0 = a4.x, ax1 = a4.y, ax2 = a4.z, ax3 = a4.w;
    const double bx0 = b4.x, bx1 = b4.y, bx2 = b4.z, bx3 = b4.w;
#pragma unroll
    for (int a = 0; a < 3; ++a) {
      const float4 wv = *reinterpret_cast<const float4*>(&lds_wd[a * 1024 + d]);
      const double w0 = wv.x, w1 = wv.y, w2 = wv.z, w3 = wv.w;
      acc[a]     += ax0 * w0 + ax1 * w1 + ax2 * w2 + ax3 * w3;
      acc[3 + a] += bx0 * w0 + bx1 * w1 + bx2 * w2 + bx3 * w3;
    }
  }

  // butterfly across the 16 q-lanes; every lane ends with all 6 totals
#pragma unroll
  for (int s = 1; s < 16; s <<= 1) {
#pragma unroll
    for (int i = 0; i < 6; ++i) acc[i] += __shfl_xor(acc[i], s, 64);
  }

  const double bd0 = (double)bias[1] - (double)bias[0];
  const double bd1 = (double)bias[3] - (double)bias[2];
  const double bd2 = (double)bias[5] - (double)bias[4];
  const double bd[3] = {bd0, bd1, bd2};

  // spread the small stores across q-lanes
  if (q < 3) {
    ldiff[(size_t)row0 * 3 + q] = (float)(acc[q] + bd[q]);
  } else if (q >= 8 && q < 11) {
    const int a = q - 8;
    ldiff[(size_t)(row0 + 1) * 3 + a] = (float)(acc[3 + a] + bd[a]);
  } else if (q == 4) {
#pragma unroll
    for (int a = 0; a < 3; ++a)
      outPred[(size_t)row0 * 3 + a] = ((float)(acc[a] + bd[a]) > 0.0f) ? 1.0f : 0.0f;
  } else if (q == 12) {
#pragma unroll
    for (int a = 0; a < 3; ++a)
      outPred[(size_t)(row0 + 1) * 3 + a] = ((float)(acc[3 + a] + bd[a]) > 0.0f) ? 1.0f : 0.0f;
  }
}

// ---------------- K2: scan + gather + loss, single block ----------------
// Positives have forced class-1 score 2.0 (> any sigmoid) and ~6144/batch >> 64,
// so top_k (lowest-index tie-break) == first 64 positives in flat order.
// Wave w owns batch w. ldiff flat index: (w*4096+seq)*3+anc == w*SA + pos.
// candidate = (ldiff>0) — bit-identical to K1's pred. loss = sum(term)/(512*2).
__global__ __launch_bounds__(512)
void k_sample_final(const int* __restrict__ labels, const float* __restrict__ ldiff,
                    float* __restrict__ outTI, float* __restrict__ outCand,
                    float* __restrict__ out0) {
  __shared__ int   s_pos[8][KSAMP];
  __shared__ float s_part[8];
  const int tid  = threadIdx.x;
  const int w    = tid >> 6;       // batch
  const int lane = tid & 63;

  int found = 0;
  for (int base = 0; base < SA && found < KSAMP; base += 64) {
    const int lab = labels[w * SA + base + lane];
    const unsigned long long m = __ballot(lab == 1);
    if (lab == 1) {
      const int rank = __popcll(m & ((1ull << lane) - 1ull));
      const int pos = found + rank;
      if (pos < KSAMP) s_pos[w][pos] = base + lane;
    }
    found += __popcll(m);
  }
  __syncthreads();

  const int pos = s_pos[w][lane];
  const int seq = pos / 3;
  const int anc = pos - seq * 3;
  const float ld = ldiff[w * SA + pos];
  const float term = fmaxf(0.0f, 5.0f - ld);

  const int gk = w * KSAMP + lane;
  outTI[gk * 3 + 0] = (float)w;
  outTI[gk * 3 + 1] = (float)seq;
  outTI[gk * 3 + 2] = (float)anc;
  outCand[gk] = (ld > 0.0f) ? 1.0f : 0.0f;

  float t = term;
#pragma unroll
  for (int s = 1; s < 64; s <<= 1) t += __shfl_xor(t, s, 64);
  if (lane == 0) s_part[w] = t;
  __syncthreads();
  if (tid == 0) {
    float tot = 0.0f;
#pragma unroll
    for (int i = 0; i < 8; ++i) tot += s_part[i];
    out0[0] = tot * (1.0f / 1024.0f);   // /512 samples /C=2
  }
}

extern "C" void kernel_launch(void* const* d_in, const int* in_sizes, int n_in,
                              void* d_out, int out_size, void* d_ws, size_t ws_size,
                              hipStream_t stream) {
  const float* X     = (const float*)d_in[0];
  const float* W     = (const float*)d_in[1];
  const float* bias  = (const float*)d_in[2];
  const int*   lab   = (const int*)d_in[3];
  float* out   = (float*)d_out;
  float* ldiff = (float*)d_ws;    // 32768*3 floats = 384 KB

  k_gemm_pred<<<1024, 256, 0, stream>>>(X, W, bias, out + PRED_OFF, ldiff);
  k_sample_final<<<1, 512, 0, stream>>>(lab, ldiff,
                                        out + TI_OFF, out + CAND_OFF, out);
}